// Round 29
// baseline (116.288 us; speedup 1.0000x reference)
//
#include <hip/hip_runtime.h>
#include <stdint.h>

typedef unsigned short u16;
typedef __attribute__((ext_vector_type(8))) __bf16 bf16x8;
typedef __attribute__((ext_vector_type(4))) float f32x4;
typedef __attribute__((ext_vector_type(4))) unsigned short u16x4;

__device__ __forceinline__ float bf2f(u16 u){
  unsigned int x = ((unsigned int)u) << 16;
  return __builtin_bit_cast(float, x);
}
__device__ __forceinline__ u16 f2bf(float f){
  return __builtin_bit_cast(u16, (__bf16)f);
}
__device__ __forceinline__ float fexp2(float x){ return __builtin_exp2f(x); }
__device__ __forceinline__ void lds_load16(const void* g, void* l){
  __builtin_amdgcn_global_load_lds(
      (const __attribute__((address_space(1))) unsigned int*)g,
      (__attribute__((address_space(3))) unsigned int*)l, 16, 0, 0);
}

// ------- fused prep: transpose w_qkv, transpose w_out, convert x -------------
__device__ __forceinline__ void transpose_body(const float* __restrict__ in,
                                               u16* __restrict__ out,
                                               int R, int C, int bx, int by,
                                               u16 (*t)[65]){
  const int c0 = bx * 64, r0 = by * 64;
  const int tid = threadIdx.x;
  const int rr = tid >> 3;
  const int cc = (tid & 7) * 8;
#pragma unroll
  for (int i = 0; i < 2; i++){
    int r = i * 32 + rr;
    const float* p = in + (size_t)(r0 + r) * C + c0 + cc;
    f32x4 v0 = *(const f32x4*)p;
    f32x4 v1 = *(const f32x4*)(p + 4);
#pragma unroll
    for (int j = 0; j < 4; j++){ t[r][cc + j] = f2bf(v0[j]); t[r][cc + 4 + j] = f2bf(v1[j]); }
  }
  __syncthreads();
#pragma unroll
  for (int i = 0; i < 2; i++){
    int c = i * 32 + rr;
    u16 tmp[8];
#pragma unroll
    for (int j = 0; j < 8; j++) tmp[j] = t[cc + j][c];
    *(bf16x8*)(out + (size_t)(c0 + c) * R + r0 + cc) = *(const bf16x8*)tmp;
  }
}

__global__ __launch_bounds__(256) void prep(const float* __restrict__ w_qkv,
                                            const float* __restrict__ w_out,
                                            const float* __restrict__ x,
                                            u16* __restrict__ wT1,
                                            u16* __restrict__ wT2,
                                            u16* __restrict__ xbf){
  __shared__ u16 t[64][65];
  const int bid = blockIdx.x;
  if (bid < 2048){
    int i = bid * 256 + threadIdx.x;
    const float* p = x + (size_t)i * 8;
    f32x4 v0 = *(const f32x4*)p;
    f32x4 v1 = *(const f32x4*)(p + 4);
    u16 tmp[8];
#pragma unroll
    for (int j = 0; j < 4; j++){ tmp[j] = f2bf(v0[j]); tmp[4 + j] = f2bf(v1[j]); }
    *(bf16x8*)(xbf + (size_t)i * 8) = *(const bf16x8*)tmp;
  } else if (bid < 2048 + 768){
    int idx = bid - 2048;
    transpose_body(w_qkv, wT1, 1024, 3072, idx % 48, idx / 48, t);
  } else {
    int idx = bid - 2816;
    transpose_body(w_out, wT2, 1024, 1024, idx % 16, idx / 16, t);
  }
}

// ------- vT[bh][d=64][s=2048] = V third of qkv (fallback when not fused) -----
__global__ __launch_bounds__(256) void v_transpose(const u16* __restrict__ qkv,
                                                   u16* __restrict__ vT){
  const int S = 2048, LD = 3072;
  __shared__ u16 t[64][65];
  const int bh = blockIdx.y;
  const int b = bh >> 4, h = bh & 15;
  const int s0 = blockIdx.x * 64;
  const u16* src = qkv + (size_t)b * S * LD + 2048 + h * 64;
  const int tid = threadIdx.x;
  const int rr = tid >> 3;
  const int cc = (tid & 7) * 8;
#pragma unroll
  for (int i = 0; i < 2; i++){
    int s = i * 32 + rr;
    bf16x8 v = *(const bf16x8*)(src + (size_t)(s0 + s) * LD + cc);
#pragma unroll
    for (int j = 0; j < 8; j++) t[s][cc + j] = __builtin_bit_cast(u16, (__bf16)v[j]);
  }
  __syncthreads();
  u16* dst = vT + (size_t)bh * 64 * S;
#pragma unroll
  for (int i = 0; i < 2; i++){
    int d = i * 32 + rr;
    u16 tmp[8];
#pragma unroll
    for (int j = 0; j < 8; j++) tmp[j] = t[cc + j][d];
    *(bf16x8*)(dst + (size_t)d * S + s0 + cc) = *(const bf16x8*)tmp;
  }
}

// -------- GEMM: BK=32, LDS double-buffered DMA staging, XCD swizzle ----------
#define GSTAGE(P_, K0_)                                                        \
  { _Pragma("unroll")                                                          \
    for (int i = 0; i < 2; i++){                                               \
      int row0 = i * 64 + w * 16;                                              \
      int row = row0 + lrow;                                                   \
      int cs = lcd ^ ((row >> 1) & 3);                                         \
      lds_load16(A  + (size_t)(bm * 128 + row) * K + (K0_) + cs * 8,           \
                 (char*)As + (P_) * 8192 + row0 * 64);                         \
      lds_load16(Bt + (size_t)(bn * 128 + row) * K + (K0_) + cs * 8,           \
                 (char*)Bs + (P_) * 8192 + row0 * 64);                         \
    } }

template<bool OUTF32, bool ROPE>
__global__ __launch_bounds__(256, 3) void gemm_bt(const u16* __restrict__ A,
                                                  const u16* __restrict__ Bt,
                                                  const float* __restrict__ bias,
                                                  void* __restrict__ Cv,
                                                  int M, int N, int K,
                                                  const float* __restrict__ cosb,
                                                  const float* __restrict__ sinb,
                                                  u16* __restrict__ vTo){
  __shared__ u16 smem[16384];               // As[2] | Bs[2]; reuse as transpose
  u16* As = smem;
  u16* Bs = smem + 8192;
  const int nx = gridDim.x;
  const int L = blockIdx.x + nx * blockIdx.y;
  const int per = (nx * gridDim.y) >> 3;
  const int wg = (L & 7) * per + (L >> 3);
  const int bn = wg % nx, bm = wg / nx;
  const int tid = threadIdx.x, w = tid >> 6, l = tid & 63;
  const int lo = l & 15, hi = l >> 4;
  const int wr = (w >> 1) * 64, wc = (w & 1) * 64;
  f32x4 acc[4][4] = {};
  const int lrow = l >> 2, lcd = l & 3;

  GSTAGE(0, 0);
  __syncthreads();
  for (int k0 = 0; k0 < K; k0 += 32){
    const int p = (k0 >> 5) & 1;
    if (k0 + 32 < K) GSTAGE(p ^ 1, k0 + 32);
    bf16x8 a[4], b[4];
#pragma unroll
    for (int mi = 0; mi < 4; mi++){
      int row = wr + mi * 16 + lo;
      unsigned byte = (unsigned)(row * 64 + hi * 16) ^ (((row >> 1) & 3) << 4);
      a[mi] = *(const bf16x8*)((const char*)As + p * 8192 + byte);
    }
#pragma unroll
    for (int ni = 0; ni < 4; ni++){
      int row = wc + ni * 16 + lo;
      unsigned byte = (unsigned)(row * 64 + hi * 16) ^ (((row >> 1) & 3) << 4);
      b[ni] = *(const bf16x8*)((const char*)Bs + p * 8192 + byte);
    }
    __builtin_amdgcn_s_setprio(1);
#pragma unroll
    for (int mi = 0; mi < 4; mi++)
#pragma unroll
      for (int ni = 0; ni < 4; ni++)
        acc[mi][ni] = __builtin_amdgcn_mfma_f32_16x16x32_bf16(a[mi], b[ni], acc[mi][ni], 0, 0, 0);
    __builtin_amdgcn_s_setprio(0);
    __syncthreads();
  }
  if (ROPE && bn < 16){
#pragma unroll
    for (int mi = 0; mi < 4; mi++){
#pragma unroll
      for (int r = 0; r < 4; r++){
        int grow = bm * 128 + wr + mi * 16 + hi * 4 + r;
        int stok = grow & 2047;
#pragma unroll
        for (int ni = 0; ni < 4; ni++){
          int col = bn * 128 + wc + ni * 16 + lo;
          float v = acc[mi][ni][r] + bias[col];
          float partner = __shfl_xor(v, 1, 64);
          int ip = (col & 63) >> 1;
          float c = cosb[stok * 32 + ip], sn = sinb[stok * 32 + ip];
          float res = (lo & 1) ? (partner * sn + v * c) : (v * c - partner * sn);
          ((u16*)Cv)[(size_t)grow * N + col] = f2bf(res);
        }
      }
    }
  } else if (ROPE && vTo != nullptr){
    const int bloc = (bm * 128) >> 11;
    const int s0g  = (bm * 128) & 2047;
#pragma unroll
    for (int H = 0; H < 2; H++){
      if ((w & 1) == H){
#pragma unroll
        for (int mi = 0; mi < 4; mi++){
#pragma unroll
          for (int ni = 0; ni < 4; ni++){
            int d = ni * 16 + lo;
            int col = bn * 128 + wc + ni * 16 + lo;
            int sb = wr + mi * 16 + hi * 4;
            u16x4 pk;
#pragma unroll
            for (int r = 0; r < 4; r++) pk[r] = f2bf(acc[mi][ni][r] + bias[col]);
            *(u16x4*)&smem[d * 128 + (sb ^ ((d & 15) << 3))] = pk;
          }
        }
      }
      __syncthreads();
      int hh = (bn - 16) * 2 + H;
      u16* dst = vTo + (size_t)(bloc * 16 + hh) * 64 * 2048;
#pragma unroll
      for (int i = 0; i < 4; i++){
        int c = tid + 256 * i;
        int d = c >> 4, sc = c & 15;
        bf16x8 v = *(const bf16x8*)&smem[d * 128 + ((sc * 8) ^ ((d & 15) << 3))];
        *(bf16x8*)(dst + (size_t)d * 2048 + s0g + sc * 8) = v;
      }
      __syncthreads();
    }
  } else {
#pragma unroll
    for (int mi = 0; mi < 4; mi++){
#pragma unroll
      for (int r = 0; r < 4; r++){
        int grow = bm * 128 + wr + mi * 16 + hi * 4 + r;
#pragma unroll
        for (int ni = 0; ni < 4; ni++){
          int col = bn * 128 + wc + ni * 16 + lo;
          float v = acc[mi][ni][r] + bias[col];
          if (OUTF32)
            ((float*)Cv)[(size_t)grow * N + col] = v;
          else
            ((u16*)Cv)[(size_t)grow * N + col] = f2bf(v);
        }
      }
    }
  }
}

// ---- flash attention: 2-wave split-K + tile pairing; PAIRED 64-key bodies ---
// Per pair: ONE softmax reduce + ONE defer-max + ONE P roundtrip (144B rows;
// banks (4lo+2hi) -> 2-way free). Critical wave: 33 -> ~17 bodies. K staging
// dbuf unchanged; stage t+2,t+3 after QK behind sched_barrier (proven order).
#define FA_DSREAD(KB_, KT_)                                                    \
  { _Pragma("unroll")                                                          \
    for (int c = 0; c < 2; c++){                                               \
      _Pragma("unroll")                                                        \
      for (int f = 0; f < 2; f++){                                             \
        int srw = f * 16 + lo;                                                 \
        unsigned byte = ((unsigned)(srw * 128 + c * 64 + hi * 16)) ^           \
                        ((lo & 7) << 4);                                       \
        KB_[c * 2 + f] = *(const bf16x8*)(                                     \
            (const char*)&Ks[w][(KT_) & 1][0] + byte);                         \
      } } }

#define FA_STAGE(KT_)                                                          \
  { _Pragma("unroll")                                                          \
    for (int i = 0; i < 4; i++)                                                \
      lds_load16(Kp + (size_t)((KT_) * 32 + i * 8 + srow8) * LD + scs * 8,     \
                 (char*)&Ks[w][(KT_) & 1][0] + i * 1024); }

#define FA_RESCALE(PMA_, PMB_, OA_, OB_, MA_, MB_)                             \
    if (!__all(fmaxf((PMA_) - MA_, (PMB_) - MB_) <= 11.5f)){                   \
      float rmA = fmaxf(PMA_, __shfl_xor(PMA_, 16, 64));                       \
      rmA = fmaxf(rmA, __shfl_xor(rmA, 32, 64));                               \
      float rmB = fmaxf(PMB_, __shfl_xor(PMB_, 16, 64));                       \
      rmB = fmaxf(rmB, __shfl_xor(rmB, 32, 64));                               \
      float mnA = fmaxf(MA_, rmA), mnB = fmaxf(MB_, rmB);                      \
      float cA = fexp2(MA_ - mnA), cB = fexp2(MB_ - mnB);                      \
      MA_ = mnA; MB_ = mnB;                                                    \
      lparA *= cA; lparB *= cB;                                                \
      float cqA[4], cqB[4];                                                    \
      _Pragma("unroll")                                                        \
      for (int r = 0; r < 4; r++){                                             \
        cqA[r] = __shfl(cA, hi * 4 + r, 64);                                   \
        cqB[r] = __shfl(cB, hi * 4 + r, 64);                                   \
      }                                                                        \
      _Pragma("unroll")                                                        \
      for (int fd = 0; fd < 4; fd++){                                          \
        _Pragma("unroll")                                                      \
        for (int r = 0; r < 4; r++){                                           \
          OA_[fd][r] *= cqA[r]; OB_[fd][r] *= cqB[r];                          \
        }                                                                      \
      }                                                                        \
    }

#define PM8(sa) fmaxf(fmaxf(fmaxf(sa[0][0], sa[0][1]), fmaxf(sa[0][2], sa[0][3])), \
                      fmaxf(fmaxf(sa[1][0], sa[1][1]), fmaxf(sa[1][2], sa[1][3])))

// paired body: tiles KT_, KT_+1 (both staged); tile0 never crosses diagonal.
#define FA_BODY2(KT_, OA_, OB_, MA_, MB_)                                      \
  {                                                                            \
    bf16x8 kb0[4], kb1[4];                                                     \
    FA_DSREAD(kb0, KT_);                                                       \
    FA_DSREAD(kb1, (KT_) + 1);                                                 \
    bf16x8 vb0[4], vb1[4];                                                     \
    _Pragma("unroll")                                                          \
    for (int fd = 0; fd < 4; fd++){                                            \
      vb0[fd] = *(const bf16x8*)(Vb + (size_t)(fd * 16 + lo) * S +             \
                                 (KT_) * 32 + hi * 8);                         \
      vb1[fd] = *(const bf16x8*)(Vb + (size_t)(fd * 16 + lo) * S +             \
                                 ((KT_) + 1) * 32 + hi * 8);                   \
    }                                                                          \
    f32x4 saA0[2] = {}, saA1[2] = {}, saB0[2] = {}, saB1[2] = {};              \
    __builtin_amdgcn_s_setprio(1);                                             \
    _Pragma("unroll")                                                          \
    for (int f = 0; f < 2; f++){                                               \
      saA0[f] = __builtin_amdgcn_mfma_f32_16x16x32_bf16(kb0[f],     qfA0, saA0[f], 0, 0, 0); \
      saB0[f] = __builtin_amdgcn_mfma_f32_16x16x32_bf16(kb0[f],     qfB0, saB0[f], 0, 0, 0); \
      saA0[f] = __builtin_amdgcn_mfma_f32_16x16x32_bf16(kb0[2 + f], qfA1, saA0[f], 0, 0, 0); \
      saB0[f] = __builtin_amdgcn_mfma_f32_16x16x32_bf16(kb0[2 + f], qfB1, saB0[f], 0, 0, 0); \
      saA1[f] = __builtin_amdgcn_mfma_f32_16x16x32_bf16(kb1[f],     qfA0, saA1[f], 0, 0, 0); \
      saB1[f] = __builtin_amdgcn_mfma_f32_16x16x32_bf16(kb1[f],     qfB0, saB1[f], 0, 0, 0); \
      saA1[f] = __builtin_amdgcn_mfma_f32_16x16x32_bf16(kb1[2 + f], qfA1, saA1[f], 0, 0, 0); \
      saB1[f] = __builtin_amdgcn_mfma_f32_16x16x32_bf16(kb1[2 + f], qfB1, saB1[f], 0, 0, 0); \
    }                                                                          \
    __builtin_amdgcn_s_setprio(0);                                             \
    __builtin_amdgcn_sched_barrier(0);                                         \
    if ((KT_) + 2 < k1) FA_STAGE((KT_) + 2);                                   \
    if ((KT_) + 3 < k1) FA_STAGE((KT_) + 3);                                   \
    if ((KT_) + 1 == nkt - 1){                                                 \
      _Pragma("unroll")                                                        \
      for (int f = 0; f < 2; f++){                                             \
        int key0 = ((KT_) + 1) * 32 + f * 16 + hi * 4;                         \
        _Pragma("unroll")                                                      \
        for (int r = 0; r < 4; r++){                                           \
          if (key0 + r > qrA) saA1[f][r] = -1e30f;                             \
          if (key0 + r > qrB) saB1[f][r] = -1e30f;                             \
        }                                                                      \
      }                                                                        \
    }                                                                          \
    float pmA = fmaxf(PM8(saA0), PM8(saA1));                                   \
    float pmB = fmaxf(PM8(saB0), PM8(saB1));                                   \
    FA_RESCALE(pmA, pmB, OA_, OB_, MA_, MB_);                                  \
    float pvA0[2][4], pvA1[2][4], pvB0[2][4], pvB1[2][4];                      \
    _Pragma("unroll")                                                          \
    for (int f = 0; f < 2; f++){                                               \
      _Pragma("unroll")                                                        \
      for (int r = 0; r < 4; r++){                                             \
        pvA0[f][r] = fexp2(saA0[f][r] - MA_);                                  \
        pvA1[f][r] = fexp2(saA1[f][r] - MA_);                                  \
        pvB0[f][r] = fexp2(saB0[f][r] - MB_);                                  \
        pvB1[f][r] = fexp2(saB1[f][r] - MB_);                                  \
      }                                                                        \
    }                                                                          \
    _Pragma("unroll")                                                          \
    for (int f = 0; f < 2; f++){                                               \
      u16x4 pkA0, pkA1, pkB0, pkB1;                                            \
      _Pragma("unroll")                                                        \
      for (int r = 0; r < 4; r++){                                             \
        pkA0[r] = f2bf(pvA0[f][r]); pkA1[r] = f2bf(pvA1[f][r]);                \
        pkB0[r] = f2bf(pvB0[f][r]); pkB1[r] = f2bf(pvB1[f][r]);                \
      }                                                                        \
      *(u16x4*)((char*)&Ps[w][0][0] + lo * 144 + f * 32 + hi * 8) = pkA0;      \
      *(u16x4*)((char*)&Ps[w][0][0] + lo * 144 + 64 + f * 32 + hi * 8) = pkA1; \
      *(u16x4*)((char*)&Ps[w][1][0] + lo * 144 + f * 32 + hi * 8) = pkB0;      \
      *(u16x4*)((char*)&Ps[w][1][0] + lo * 144 + 64 + f * 32 + hi * 8) = pkB1; \
    }                                                                          \
    lparA += (((pvA0[0][0] + pvA0[0][1]) + (pvA0[0][2] + pvA0[0][3]))          \
            + ((pvA0[1][0] + pvA0[1][1]) + (pvA0[1][2] + pvA0[1][3])))         \
           + (((pvA1[0][0] + pvA1[0][1]) + (pvA1[0][2] + pvA1[0][3]))          \
            + ((pvA1[1][0] + pvA1[1][1]) + (pvA1[1][2] + pvA1[1][3])));        \
    lparB += (((pvB0[0][0] + pvB0[0][1]) + (pvB0[0][2] + pvB0[0][3]))          \
            + ((pvB0[1][0] + pvB0[1][1]) + (pvB0[1][2] + pvB0[1][3])))         \
           + (((pvB1[0][0] + pvB1[0][1]) + (pvB1[0][2] + pvB1[0][3]))          \
            + ((pvB1[1][0] + pvB1[1][1]) + (pvB1[1][2] + pvB1[1][3])));        \
    bf16x8 paA0 = *(const bf16x8*)((const char*)&Ps[w][0][0] + lo * 144 + hi * 16);      \
    bf16x8 paA1 = *(const bf16x8*)((const char*)&Ps[w][0][0] + lo * 144 + 64 + hi * 16); \
    bf16x8 paB0 = *(const bf16x8*)((const char*)&Ps[w][1][0] + lo * 144 + hi * 16);      \
    bf16x8 paB1 = *(const bf16x8*)((const char*)&Ps[w][1][0] + lo * 144 + 64 + hi * 16); \
    __builtin_amdgcn_s_setprio(1);                                             \
    _Pragma("unroll")                                                          \
    for (int fd = 0; fd < 4; fd++){                                            \
      OA_[fd] = __builtin_amdgcn_mfma_f32_16x16x32_bf16(paA0, vb0[fd], OA_[fd], 0, 0, 0); \
      OB_[fd] = __builtin_amdgcn_mfma_f32_16x16x32_bf16(paB0, vb0[fd], OB_[fd], 0, 0, 0); \
      OA_[fd] = __builtin_amdgcn_mfma_f32_16x16x32_bf16(paA1, vb1[fd], OA_[fd], 0, 0, 0); \
      OB_[fd] = __builtin_amdgcn_mfma_f32_16x16x32_bf16(paB1, vb1[fd], OB_[fd], 0, 0, 0); \
    }                                                                          \
    __builtin_amdgcn_s_setprio(0);                                             \
  }

// single-tile tail body (tile KT_ already staged)
#define FA_BODY1(KT_, OA_, OB_, MA_, MB_)                                      \
  {                                                                            \
    bf16x8 kbt[4];                                                             \
    FA_DSREAD(kbt, KT_);                                                       \
    bf16x8 vbt[4];                                                             \
    _Pragma("unroll")                                                          \
    for (int fd = 0; fd < 4; fd++)                                             \
      vbt[fd] = *(const bf16x8*)(Vb + (size_t)(fd * 16 + lo) * S +             \
                                 (KT_) * 32 + hi * 8);                         \
    f32x4 saA[2] = {}, saB[2] = {};                                            \
    __builtin_amdgcn_s_setprio(1);                                             \
    _Pragma("unroll")                                                          \
    for (int f = 0; f < 2; f++){                                               \
      saA[f] = __builtin_amdgcn_mfma_f32_16x16x32_bf16(kbt[f],     qfA0, saA[f], 0, 0, 0); \
      saB[f] = __builtin_amdgcn_mfma_f32_16x16x32_bf16(kbt[f],     qfB0, saB[f], 0, 0, 0); \
      saA[f] = __builtin_amdgcn_mfma_f32_16x16x32_bf16(kbt[2 + f], qfA1, saA[f], 0, 0, 0); \
      saB[f] = __builtin_amdgcn_mfma_f32_16x16x32_bf16(kbt[2 + f], qfB1, saB[f], 0, 0, 0); \
    }                                                                          \
    __builtin_amdgcn_s_setprio(0);                                             \
    if ((KT_) == nkt - 1){                                                     \
      _Pragma("unroll")                                                        \
      for (int f = 0; f < 2; f++){                                             \
        int key0 = (KT_) * 32 + f * 16 + hi * 4;                               \
        _Pragma("unroll")                                                      \
        for (int r = 0; r < 4; r++){                                           \
          if (key0 + r > qrA) saA[f][r] = -1e30f;                              \
          if (key0 + r > qrB) saB[f][r] = -1e30f;                              \
        }                                                                      \
      }                                                                        \
    }                                                                          \
    float pmA = PM8(saA);                                                      \
    float pmB = PM8(saB);                                                      \
    FA_RESCALE(pmA, pmB, OA_, OB_, MA_, MB_);                                  \
    float pvA[2][4], pvB[2][4];                                                \
    _Pragma("unroll")                                                          \
    for (int f = 0; f < 2; f++){                                               \
      _Pragma("unroll")                                                        \
      for (int r = 0; r < 4; r++){                                             \
        pvA[f][r] = fexp2(saA[f][r] - MA_);                                    \
        pvB[f][r] = fexp2(saB[f][r] - MB_);                                    \
      }                                                                        \
    }                                                                          \
    _Pragma("unroll")                                                          \
    for (int f = 0; f < 2; f++){                                               \
      u16x4 pkA, pkB;                                                          \
      _Pragma("unroll")                                                        \
      for (int r = 0; r < 4; r++){                                             \
        pkA[r] = f2bf(pvA[f][r]); pkB[r] = f2bf(pvB[f][r]);                    \
      }                                                                        \
      *(u16x4*)((char*)&Ps[w][0][0] + lo * 144 + f * 32 + hi * 8) = pkA;       \
      *(u16x4*)((char*)&Ps[w][1][0] + lo * 144 + f * 32 + hi * 8) = pkB;       \
    }                                                                          \
    lparA += ((pvA[0][0] + pvA[0][1]) + (pvA[0][2] + pvA[0][3]))               \
           + ((pvA[1][0] + pvA[1][1]) + (pvA[1][2] + pvA[1][3]));              \
    lparB += ((pvB[0][0] + pvB[0][1]) + (pvB[0][2] + pvB[0][3]))               \
           + ((pvB[1][0] + pvB[1][1]) + (pvB[1][2] + pvB[1][3]));              \
    bf16x8 paA = *(const bf16x8*)((const char*)&Ps[w][0][0] + lo * 144 + hi * 16); \
    bf16x8 paB = *(const bf16x8*)((const char*)&Ps[w][1][0] + lo * 144 + hi * 16); \
    __builtin_amdgcn_s_setprio(1);                                             \
    _Pragma("unroll")                                                          \
    for (int fd = 0; fd < 4; fd++){                                            \
      OA_[fd] = __builtin_amdgcn_mfma_f32_16x16x32_bf16(paA, vbt[fd], OA_[fd], 0, 0, 0); \
      OB_[fd] = __builtin_amdgcn_mfma_f32_16x16x32_bf16(paB, vbt[fd], OB_[fd], 0, 0, 0); \
    }                                                                          \
    __builtin_amdgcn_s_setprio(0);                                             \
  }

#define FA_PHASE(T_, OA_, OB_, MA_, MB_, LA_, LB_)                             \
  {                                                                            \
    const int q0p = (T_) * 32;                                                 \
    const int qrA = q0p + lo, qrB = q0p + 16 + lo;                             \
    const int nkt = (T_) + 1;                                                  \
    const int ch = (nkt + 1) >> 1;                                             \
    const int k0 = w ? ch : 0;                                                 \
    const int k1 = w ? nkt : ch;                                               \
    bf16x8 qfA0, qfA1, qfB0, qfB1;                                             \
    {                                                                          \
      bf16x8 va0 = *(const bf16x8*)(Qp + (size_t)qrA * LD + hi * 8);           \
      bf16x8 va1 = *(const bf16x8*)(Qp + (size_t)qrA * LD + 32 + hi * 8);      \
      bf16x8 vb0 = *(const bf16x8*)(Qp + (size_t)qrB * LD + hi * 8);           \
      bf16x8 vb1 = *(const bf16x8*)(Qp + (size_t)qrB * LD + 32 + hi * 8);      \
      _Pragma("unroll")                                                        \
      for (int j = 0; j < 8; j++){                                             \
        qfA0[j] = (__bf16)((float)va0[j] * QSC);                               \
        qfA1[j] = (__bf16)((float)va1[j] * QSC);                               \
        qfB0[j] = (__bf16)((float)vb0[j] * QSC);                               \
        qfB1[j] = (__bf16)((float)vb1[j] * QSC);                               \
      }                                                                        \
    }                                                                          \
    float lparA = 0.f, lparB = 0.f;                                            \
    MA_ = -1e30f; MB_ = -1e30f;                                                \
    int kt = k0;                                                               \
    if (kt < k1){                                                              \
      FA_STAGE(kt);                                                            \
      if (kt + 1 < k1) FA_STAGE(kt + 1);                                       \
      while (kt + 1 < k1){                                                     \
        FA_BODY2(kt, OA_, OB_, MA_, MB_);                                      \
        kt += 2;                                                               \
      }                                                                        \
      if (kt < k1){                                                            \
        FA_BODY1(kt, OA_, OB_, MA_, MB_);                                      \
      }                                                                        \
    }                                                                          \
    lparA += __shfl_xor(lparA, 16, 64); lparA += __shfl_xor(lparA, 32, 64);    \
    lparB += __shfl_xor(lparB, 16, 64); lparB += __shfl_xor(lparB, 32, 64);    \
    LA_ = lparA; LB_ = lparB;                                                  \
  }

#define FA_WRITEPART(slot_, OA_, OB_, MA_, MB_, LA_, LB_)                      \
  {                                                                            \
    _Pragma("unroll")                                                          \
    for (int fd = 0; fd < 4; fd++){                                            \
      u16x4 pkA, pkB;                                                          \
      _Pragma("unroll")                                                        \
      for (int r = 0; r < 4; r++){                                             \
        pkA[r] = f2bf(OA_[fd][r]); pkB[r] = f2bf(OB_[fd][r]);                  \
      }                                                                        \
      *(u16x4*)((char*)&Xo[slot_][0] + (fd * 16 + lo) * 72 + hi * 8) = pkA;    \
      *(u16x4*)((char*)&Xo[slot_][0] + (fd * 16 + lo) * 72 + 32 + hi * 8) = pkB;\
    }                                                                          \
    if (hi == 0){                                                              \
      Xm[slot_][lo] = MA_;      Xl[slot_][lo] = LA_;                           \
      Xm[slot_][16 + lo] = MB_; Xl[slot_][16 + lo] = LB_;                      \
    }                                                                          \
  }

#define FA_COMBINE(slot_, T_, OA_, OB_, MA_, MB_, LA_, LB_)                    \
  {                                                                            \
    const int q0p = (T_) * 32;                                                 \
    u16x4 pA[4], pB[4];                                                        \
    _Pragma("unroll")                                                          \
    for (int fd = 0; fd < 4; fd++){                                            \
      pA[fd] = *(const u16x4*)((const char*)&Xo[slot_][0] +                    \
                               (fd * 16 + lo) * 72 + hi * 8);                  \
      pB[fd] = *(const u16x4*)((const char*)&Xo[slot_][0] +                    \
                               (fd * 16 + lo) * 72 + 32 + hi * 8);             \
    }                                                                          \
    _Pragma("unroll")                                                          \
    for (int r = 0; r < 4; r++){                                               \
      float mOA = __shfl(MA_, hi * 4 + r, 64);                                 \
      float lOA = __shfl(LA_, hi * 4 + r, 64);                                 \
      float mOB = __shfl(MB_, hi * 4 + r, 64);                                 \
      float lOB = __shfl(LB_, hi * 4 + r, 64);                                 \
      float mPA = Xm[slot_][hi * 4 + r], lPA = Xl[slot_][hi * 4 + r];          \
      float mPB = Xm[slot_][16 + hi * 4 + r], lPB = Xl[slot_][16 + hi * 4 + r];\
      float MfA = fmaxf(mOA, mPA), MfB = fmaxf(mOB, mPB);                      \
      float c0A = fexp2(mOA - MfA), c1A = fexp2(mPA - MfA);                    \
      float c0B = fexp2(mOB - MfB), c1B = fexp2(mPB - MfB);                    \
      float invA = 1.0f / (lOA * c0A + lPA * c1A);                             \
      float invB = 1.0f / (lOB * c0B + lPB * c1B);                             \
      int srA = q0p + hi * 4 + r;                                              \
      int srB = q0p + 16 + hi * 4 + r;                                         \
      u16* orA = Oout + (size_t)(b * S + srA) * 1024 + h * 64;                 \
      u16* orB = Oout + (size_t)(b * S + srB) * 1024 + h * 64;                 \
      _Pragma("unroll")                                                        \
      for (int fd = 0; fd < 4; fd++){                                          \
        float vA = (OA_[fd][r] * c0A + bf2f(pA[fd][r]) * c1A) * invA;          \
        float vB = (OB_[fd][r] * c0B + bf2f(pB[fd][r]) * c1B) * invB;          \
        orA[fd * 16 + lo] = f2bf(vA);                                          \
        orB[fd * 16 + lo] = f2bf(vB);                                          \
      }                                                                        \
    }                                                                          \
  }

__global__ __launch_bounds__(128, 2) void flash_attn(const u16* __restrict__ qkv,
                                                     const u16* __restrict__ vT,
                                                     u16* __restrict__ Oout){
  const int S = 2048, LD = 3072;
  const int L = blockIdx.x;
  const int bh = L & 31;
  const int bx = L >> 5;                    // 0..31
  const int b = bh >> 4, h = bh & 15;
  const u16* base = qkv + (size_t)b * S * LD;
  const u16* Qp = base + h * 64;
  const u16* Kp = base + 1024 + h * 64;
  const u16* Vb = vT + (size_t)bh * 64 * S;
  const int tid = threadIdx.x, w = tid >> 6, l = tid & 63;
  const int lo = l & 15, hi = l >> 4;
  __shared__ u16 Ks[2][2][32 * 64];         // [wave][buf]
  __shared__ u16 Ps[2][2][16 * 72];         // [wave][subtile], 144B rows
  __shared__ u16 Xo[2][64 * 36];            // [slot] partial O, 72B rows
  __shared__ float Xm[2][32], Xl[2][32];

  const float QSC = 0.125f * 1.44269504089f;
  const int srow8 = l >> 3;
  const int scs = (l & 7) ^ srow8;

  f32x4 o1A[4] = {}, o1B[4] = {};           // phase1 (T0) partial
  f32x4 o2A[4] = {}, o2B[4] = {};           // phase2 (T1) partial
  float m1A, m1B, l1A, l1B, m2A, m2B, l2A, l2B;

  FA_PHASE(63 - bx, o1A, o1B, m1A, m1B, l1A, l1B);
  if (w == 1) FA_WRITEPART(0, o1A, o1B, m1A, m1B, l1A, l1B);
  FA_PHASE(bx,      o2A, o2B, m2A, m2B, l2A, l2B);
  if (w == 0) FA_WRITEPART(1, o2A, o2B, m2A, m2B, l2A, l2B);
  __syncthreads();
  if (w == 0){
    FA_COMBINE(0, 63 - bx, o1A, o1B, m1A, m1B, l1A, l1B);
  } else {
    FA_COMBINE(1, bx,      o2A, o2B, m2A, m2B, l2A, l2B);
  }
}

extern "C" void kernel_launch(void* const* d_in, const int* in_sizes, int n_in,
                              void* d_out, int out_size, void* d_ws, size_t ws_size,
                              hipStream_t stream){
  const float* x     = (const float*)d_in[0];
  const float* w_qkv = (const float*)d_in[1];
  const float* b_qkv = (const float*)d_in[2];
  const float* w_out = (const float*)d_in[3];
  const float* b_out = (const float*)d_in[4];
  const float* cosb  = (const float*)d_in[5];
  const float* sinb  = (const float*)d_in[6];
  // d_in[7] = mask: causal, implemented analytically.
  float* out = (float*)d_out;
  char* ws = (char*)d_ws;
  u16* qkv  = (u16*)(ws);               // bf16 [4096][3072]   25.2 MB
  u16* attn = (u16*)(ws + 25165824);    // bf16 [4096][1024]    8.4 MB
  u16* xbf  = attn;                     // x bf16 — dead before flash writes attn
  u16* wT2  = (u16*)(ws + 33554432);    // w_out^T bf16 [1024][1024]  2.1 MB
  u16* wT1  = (u16*)(ws + 35651584);    // w_qkv^T bf16 [3072][1024]  6.3 MB

  const bool fuse = ws_size >= (size_t)50331648;   // 48 MB
  u16* vT = fuse ? (u16*)(ws + 41943040)           // after wT1
                 : (u16*)(ws + 35651584);          // alias wT1 (dead post-GEMM1)

  prep<<<3072, 256, 0, stream>>>(w_qkv, w_out, x, wT1, wT2, xbf);
  gemm_bt<false, true ><<<dim3(24, 32), 256, 0, stream>>>(
      xbf, wT1, b_qkv, qkv, 4096, 3072, 1024, cosb, sinb, fuse ? vT : nullptr);
  if (!fuse)
    v_transpose<<<dim3(32, 32), 256, 0, stream>>>(qkv, vT);
  flash_attn<<<1024, 128, 0, stream>>>(qkv, vT, attn);
  gemm_bt<true , false><<<dim3(8, 32), 256, 0, stream>>>(
      attn, wT2, b_out, out, 4096, 1024, 1024, cosb, sinb, nullptr);
}

// Round 30
// 115.027 us; speedup vs baseline: 1.0110x; 1.0110x over previous
//
#include <hip/hip_runtime.h>
#include <stdint.h>

typedef unsigned short u16;
typedef __attribute__((ext_vector_type(8))) __bf16 bf16x8;
typedef __attribute__((ext_vector_type(4))) float f32x4;
typedef __attribute__((ext_vector_type(4))) unsigned short u16x4;

__device__ __forceinline__ float bf2f(u16 u){
  unsigned int x = ((unsigned int)u) << 16;
  return __builtin_bit_cast(float, x);
}
__device__ __forceinline__ u16 f2bf(float f){
  return __builtin_bit_cast(u16, (__bf16)f);
}
__device__ __forceinline__ float fexp2(float x){ return __builtin_exp2f(x); }
__device__ __forceinline__ void lds_load16(const void* g, void* l){
  __builtin_amdgcn_global_load_lds(
      (const __attribute__((address_space(1))) unsigned int*)g,
      (__attribute__((address_space(3))) unsigned int*)l, 16, 0, 0);
}

// ------- fused prep: transpose w_qkv, transpose w_out, convert x -------------
__device__ __forceinline__ void transpose_body(const float* __restrict__ in,
                                               u16* __restrict__ out,
                                               int R, int C, int bx, int by,
                                               u16 (*t)[65]){
  const int c0 = bx * 64, r0 = by * 64;
  const int tid = threadIdx.x;
  const int rr = tid >> 3;
  const int cc = (tid & 7) * 8;
#pragma unroll
  for (int i = 0; i < 2; i++){
    int r = i * 32 + rr;
    const float* p = in + (size_t)(r0 + r) * C + c0 + cc;
    f32x4 v0 = *(const f32x4*)p;
    f32x4 v1 = *(const f32x4*)(p + 4);
#pragma unroll
    for (int j = 0; j < 4; j++){ t[r][cc + j] = f2bf(v0[j]); t[r][cc + 4 + j] = f2bf(v1[j]); }
  }
  __syncthreads();
#pragma unroll
  for (int i = 0; i < 2; i++){
    int c = i * 32 + rr;
    u16 tmp[8];
#pragma unroll
    for (int j = 0; j < 8; j++) tmp[j] = t[cc + j][c];
    *(bf16x8*)(out + (size_t)(c0 + c) * R + r0 + cc) = *(const bf16x8*)tmp;
  }
}

__global__ __launch_bounds__(256) void prep(const float* __restrict__ w_qkv,
                                            const float* __restrict__ w_out,
                                            const float* __restrict__ x,
                                            u16* __restrict__ wT1,
                                            u16* __restrict__ wT2,
                                            u16* __restrict__ xbf){
  __shared__ u16 t[64][65];
  const int bid = blockIdx.x;
  if (bid < 2048){
    int i = bid * 256 + threadIdx.x;
    const float* p = x + (size_t)i * 8;
    f32x4 v0 = *(const f32x4*)p;
    f32x4 v1 = *(const f32x4*)(p + 4);
    u16 tmp[8];
#pragma unroll
    for (int j = 0; j < 4; j++){ tmp[j] = f2bf(v0[j]); tmp[4 + j] = f2bf(v1[j]); }
    *(bf16x8*)(xbf + (size_t)i * 8) = *(const bf16x8*)tmp;
  } else if (bid < 2048 + 768){
    int idx = bid - 2048;
    transpose_body(w_qkv, wT1, 1024, 3072, idx % 48, idx / 48, t);
  } else {
    int idx = bid - 2816;
    transpose_body(w_out, wT2, 1024, 1024, idx % 16, idx / 16, t);
  }
}

// ------- vT[bh][d=64][s=2048] = V third of qkv (fallback when not fused) -----
__global__ __launch_bounds__(256) void v_transpose(const u16* __restrict__ qkv,
                                                   u16* __restrict__ vT){
  const int S = 2048, LD = 3072;
  __shared__ u16 t[64][65];
  const int bh = blockIdx.y;
  const int b = bh >> 4, h = bh & 15;
  const int s0 = blockIdx.x * 64;
  const u16* src = qkv + (size_t)b * S * LD + 2048 + h * 64;
  const int tid = threadIdx.x;
  const int rr = tid >> 3;
  const int cc = (tid & 7) * 8;
#pragma unroll
  for (int i = 0; i < 2; i++){
    int s = i * 32 + rr;
    bf16x8 v = *(const bf16x8*)(src + (size_t)(s0 + s) * LD + cc);
#pragma unroll
    for (int j = 0; j < 8; j++) t[s][cc + j] = __builtin_bit_cast(u16, (__bf16)v[j]);
  }
  __syncthreads();
  u16* dst = vT + (size_t)bh * 64 * S;
#pragma unroll
  for (int i = 0; i < 2; i++){
    int d = i * 32 + rr;
    u16 tmp[8];
#pragma unroll
    for (int j = 0; j < 8; j++) tmp[j] = t[cc + j][d];
    *(bf16x8*)(dst + (size_t)d * S + s0 + cc) = *(const bf16x8*)tmp;
  }
}

// -------- GEMM: BK=32, LDS double-buffered DMA staging, XCD swizzle ----------
#define GSTAGE(P_, K0_)                                                        \
  { _Pragma("unroll")                                                          \
    for (int i = 0; i < 2; i++){                                               \
      int row0 = i * 64 + w * 16;                                              \
      int row = row0 + lrow;                                                   \
      int cs = lcd ^ ((row >> 1) & 3);                                         \
      lds_load16(A  + (size_t)(bm * 128 + row) * K + (K0_) + cs * 8,           \
                 (char*)As + (P_) * 8192 + row0 * 64);                         \
      lds_load16(Bt + (size_t)(bn * 128 + row) * K + (K0_) + cs * 8,           \
                 (char*)Bs + (P_) * 8192 + row0 * 64);                         \
    } }

template<bool OUTF32, bool ROPE>
__global__ __launch_bounds__(256, 3) void gemm_bt(const u16* __restrict__ A,
                                                  const u16* __restrict__ Bt,
                                                  const float* __restrict__ bias,
                                                  void* __restrict__ Cv,
                                                  int M, int N, int K,
                                                  const float* __restrict__ cosb,
                                                  const float* __restrict__ sinb,
                                                  u16* __restrict__ vTo){
  __shared__ u16 smem[16384];               // As[2] | Bs[2]; reuse as transpose
  u16* As = smem;
  u16* Bs = smem + 8192;
  const int nx = gridDim.x;
  const int L = blockIdx.x + nx * blockIdx.y;
  const int per = (nx * gridDim.y) >> 3;
  const int wg = (L & 7) * per + (L >> 3);
  const int bn = wg % nx, bm = wg / nx;
  const int tid = threadIdx.x, w = tid >> 6, l = tid & 63;
  const int lo = l & 15, hi = l >> 4;
  const int wr = (w >> 1) * 64, wc = (w & 1) * 64;
  f32x4 acc[4][4] = {};
  const int lrow = l >> 2, lcd = l & 3;

  GSTAGE(0, 0);
  __syncthreads();
  for (int k0 = 0; k0 < K; k0 += 32){
    const int p = (k0 >> 5) & 1;
    if (k0 + 32 < K) GSTAGE(p ^ 1, k0 + 32);
    bf16x8 a[4], b[4];
#pragma unroll
    for (int mi = 0; mi < 4; mi++){
      int row = wr + mi * 16 + lo;
      unsigned byte = (unsigned)(row * 64 + hi * 16) ^ (((row >> 1) & 3) << 4);
      a[mi] = *(const bf16x8*)((const char*)As + p * 8192 + byte);
    }
#pragma unroll
    for (int ni = 0; ni < 4; ni++){
      int row = wc + ni * 16 + lo;
      unsigned byte = (unsigned)(row * 64 + hi * 16) ^ (((row >> 1) & 3) << 4);
      b[ni] = *(const bf16x8*)((const char*)Bs + p * 8192 + byte);
    }
    __builtin_amdgcn_s_setprio(1);
#pragma unroll
    for (int mi = 0; mi < 4; mi++)
#pragma unroll
      for (int ni = 0; ni < 4; ni++)
        acc[mi][ni] = __builtin_amdgcn_mfma_f32_16x16x32_bf16(a[mi], b[ni], acc[mi][ni], 0, 0, 0);
    __builtin_amdgcn_s_setprio(0);
    __syncthreads();
  }
  if (ROPE && bn < 16){
#pragma unroll
    for (int mi = 0; mi < 4; mi++){
#pragma unroll
      for (int r = 0; r < 4; r++){
        int grow = bm * 128 + wr + mi * 16 + hi * 4 + r;
        int stok = grow & 2047;
#pragma unroll
        for (int ni = 0; ni < 4; ni++){
          int col = bn * 128 + wc + ni * 16 + lo;
          float v = acc[mi][ni][r] + bias[col];
          float partner = __shfl_xor(v, 1, 64);
          int ip = (col & 63) >> 1;
          float c = cosb[stok * 32 + ip], sn = sinb[stok * 32 + ip];
          float res = (lo & 1) ? (partner * sn + v * c) : (v * c - partner * sn);
          ((u16*)Cv)[(size_t)grow * N + col] = f2bf(res);
        }
      }
    }
  } else if (ROPE && vTo != nullptr){
    const int bloc = (bm * 128) >> 11;
    const int s0g  = (bm * 128) & 2047;
#pragma unroll
    for (int H = 0; H < 2; H++){
      if ((w & 1) == H){
#pragma unroll
        for (int mi = 0; mi < 4; mi++){
#pragma unroll
          for (int ni = 0; ni < 4; ni++){
            int d = ni * 16 + lo;
            int col = bn * 128 + wc + ni * 16 + lo;
            int sb = wr + mi * 16 + hi * 4;
            u16x4 pk;
#pragma unroll
            for (int r = 0; r < 4; r++) pk[r] = f2bf(acc[mi][ni][r] + bias[col]);
            *(u16x4*)&smem[d * 128 + (sb ^ ((d & 15) << 3))] = pk;
          }
        }
      }
      __syncthreads();
      int hh = (bn - 16) * 2 + H;
      u16* dst = vTo + (size_t)(bloc * 16 + hh) * 64 * 2048;
#pragma unroll
      for (int i = 0; i < 4; i++){
        int c = tid + 256 * i;
        int d = c >> 4, sc = c & 15;
        bf16x8 v = *(const bf16x8*)&smem[d * 128 + ((sc * 8) ^ ((d & 15) << 3))];
        *(bf16x8*)(dst + (size_t)d * 2048 + s0g + sc * 8) = v;
      }
      __syncthreads();
    }
  } else {
#pragma unroll
    for (int mi = 0; mi < 4; mi++){
#pragma unroll
      for (int r = 0; r < 4; r++){
        int grow = bm * 128 + wr + mi * 16 + hi * 4 + r;
#pragma unroll
        for (int ni = 0; ni < 4; ni++){
          int col = bn * 128 + wc + ni * 16 + lo;
          float v = acc[mi][ni][r] + bias[col];
          if (OUTF32)
            ((float*)Cv)[(size_t)grow * N + col] = v;
          else
            ((u16*)Cv)[(size_t)grow * N + col] = f2bf(v);
        }
      }
    }
  }
}

// ---- flash attention (r24/r28 best): 2-wave blocks, split-K + tile pairing,
// K-fragment register prefetch, DMA staged 2 ahead behind sched_barrier ------
#define FA_DSREAD(KB_, KT_)                                                    \
  { _Pragma("unroll")                                                          \
    for (int c = 0; c < 2; c++){                                               \
      _Pragma("unroll")                                                        \
      for (int f = 0; f < 2; f++){                                             \
        int srw = f * 16 + lo;                                                 \
        unsigned byte = ((unsigned)(srw * 128 + c * 64 + hi * 16)) ^           \
                        ((lo & 7) << 4);                                       \
        KB_[c * 2 + f] = *(const bf16x8*)(                                     \
            (const char*)&Ks[w][(KT_) & 1][0] + byte);                         \
      } } }

#define FA_STAGE(KT_)                                                          \
  { _Pragma("unroll")                                                          \
    for (int i = 0; i < 4; i++)                                                \
      lds_load16(Kp + (size_t)((KT_) * 32 + i * 8 + srow8) * LD + scs * 8,     \
                 (char*)&Ks[w][(KT_) & 1][0] + i * 1024); }

#define FA_BODY(KBU_, KBL_, KT_, OA_, OB_, MA_, MB_)                           \
  {                                                                            \
    bf16x8 vb[4];                                                              \
    _Pragma("unroll")                                                          \
    for (int fd = 0; fd < 4; fd++)                                             \
      vb[fd] = *(const bf16x8*)(Vb + (size_t)(fd * 16 + lo) * S +              \
                                (KT_) * 32 + hi * 8);                          \
    if ((KT_) + 1 < k1) FA_DSREAD(KBL_, (KT_) + 1);                            \
    f32x4 saA[2] = {}, saB[2] = {};                                            \
    __builtin_amdgcn_s_setprio(1);                                             \
    saA[0] = __builtin_amdgcn_mfma_f32_16x16x32_bf16(KBU_[0], qfA0, saA[0], 0, 0, 0); \
    saB[0] = __builtin_amdgcn_mfma_f32_16x16x32_bf16(KBU_[0], qfB0, saB[0], 0, 0, 0); \
    saA[0] = __builtin_amdgcn_mfma_f32_16x16x32_bf16(KBU_[2], qfA1, saA[0], 0, 0, 0); \
    saB[0] = __builtin_amdgcn_mfma_f32_16x16x32_bf16(KBU_[2], qfB1, saB[0], 0, 0, 0); \
    saA[1] = __builtin_amdgcn_mfma_f32_16x16x32_bf16(KBU_[1], qfA0, saA[1], 0, 0, 0); \
    saB[1] = __builtin_amdgcn_mfma_f32_16x16x32_bf16(KBU_[1], qfB0, saB[1], 0, 0, 0); \
    saA[1] = __builtin_amdgcn_mfma_f32_16x16x32_bf16(KBU_[3], qfA1, saA[1], 0, 0, 0); \
    saB[1] = __builtin_amdgcn_mfma_f32_16x16x32_bf16(KBU_[3], qfB1, saB[1], 0, 0, 0); \
    __builtin_amdgcn_s_setprio(0);                                             \
    __builtin_amdgcn_sched_barrier(0);                                         \
    if ((KT_) + 2 < k1) FA_STAGE((KT_) + 2);                                   \
    if ((KT_) == nkt - 1){                                                     \
      _Pragma("unroll")                                                        \
      for (int f = 0; f < 2; f++){                                             \
        int key0 = (KT_) * 32 + f * 16 + hi * 4;                               \
        _Pragma("unroll")                                                      \
        for (int r = 0; r < 4; r++){                                           \
          if (key0 + r > qrA) saA[f][r] = -1e30f;                              \
          if (key0 + r > qrB) saB[f][r] = -1e30f;                              \
        }                                                                      \
      }                                                                        \
    }                                                                          \
    float pmA = fmaxf(                                                         \
        fmaxf(fmaxf(saA[0][0], saA[0][1]), fmaxf(saA[0][2], saA[0][3])),       \
        fmaxf(fmaxf(saA[1][0], saA[1][1]), fmaxf(saA[1][2], saA[1][3])));      \
    float pmB = fmaxf(                                                         \
        fmaxf(fmaxf(saB[0][0], saB[0][1]), fmaxf(saB[0][2], saB[0][3])),       \
        fmaxf(fmaxf(saB[1][0], saB[1][1]), fmaxf(saB[1][2], saB[1][3])));      \
    if (!__all(fmaxf(pmA - MA_, pmB - MB_) <= 11.5f)){                         \
      float rmA = fmaxf(pmA, __shfl_xor(pmA, 16, 64));                         \
      rmA = fmaxf(rmA, __shfl_xor(rmA, 32, 64));                               \
      float rmB = fmaxf(pmB, __shfl_xor(pmB, 16, 64));                         \
      rmB = fmaxf(rmB, __shfl_xor(rmB, 32, 64));                               \
      float mnA = fmaxf(MA_, rmA), mnB = fmaxf(MB_, rmB);                      \
      float cA = fexp2(MA_ - mnA), cB = fexp2(MB_ - mnB);                      \
      MA_ = mnA; MB_ = mnB;                                                    \
      lparA *= cA; lparB *= cB;                                                \
      float cqA[4], cqB[4];                                                    \
      _Pragma("unroll")                                                        \
      for (int r = 0; r < 4; r++){                                             \
        cqA[r] = __shfl(cA, hi * 4 + r, 64);                                   \
        cqB[r] = __shfl(cB, hi * 4 + r, 64);                                   \
      }                                                                        \
      _Pragma("unroll")                                                        \
      for (int fd = 0; fd < 4; fd++){                                          \
        _Pragma("unroll")                                                      \
        for (int r = 0; r < 4; r++){                                           \
          OA_[fd][r] *= cqA[r]; OB_[fd][r] *= cqB[r];                          \
        }                                                                      \
      }                                                                        \
    }                                                                          \
    float pvA[2][4], pvB[2][4];                                                \
    _Pragma("unroll")                                                          \
    for (int f = 0; f < 2; f++){                                               \
      _Pragma("unroll")                                                        \
      for (int r = 0; r < 4; r++){                                             \
        pvA[f][r] = fexp2(saA[f][r] - MA_);                                    \
        pvB[f][r] = fexp2(saB[f][r] - MB_);                                    \
      }                                                                        \
    }                                                                          \
    _Pragma("unroll")                                                          \
    for (int f = 0; f < 2; f++){                                               \
      u16x4 pkA, pkB;                                                          \
      _Pragma("unroll")                                                        \
      for (int r = 0; r < 4; r++){                                             \
        pkA[r] = f2bf(pvA[f][r]); pkB[r] = f2bf(pvB[f][r]);                    \
      }                                                                        \
      *(u16x4*)((char*)&Ps[w][0][0] + lo * 72 + f * 32 + hi * 8) = pkA;        \
      *(u16x4*)((char*)&Ps[w][1][0] + lo * 72 + f * 32 + hi * 8) = pkB;        \
    }                                                                          \
    lparA += ((pvA[0][0] + pvA[0][1]) + (pvA[0][2] + pvA[0][3]))               \
           + ((pvA[1][0] + pvA[1][1]) + (pvA[1][2] + pvA[1][3]));              \
    lparB += ((pvB[0][0] + pvB[0][1]) + (pvB[0][2] + pvB[0][3]))               \
           + ((pvB[1][0] + pvB[1][1]) + (pvB[1][2] + pvB[1][3]));              \
    bf16x8 paA = *(const bf16x8*)((const char*)&Ps[w][0][0] + lo * 72 +        \
                                  hi * 16);                                    \
    bf16x8 paB = *(const bf16x8*)((const char*)&Ps[w][1][0] + lo * 72 +        \
                                  hi * 16);                                    \
    __builtin_amdgcn_s_setprio(1);                                             \
    _Pragma("unroll")                                                          \
    for (int fd = 0; fd < 4; fd++){                                            \
      OA_[fd] = __builtin_amdgcn_mfma_f32_16x16x32_bf16(paA, vb[fd],           \
                                                        OA_[fd], 0, 0, 0);     \
      OB_[fd] = __builtin_amdgcn_mfma_f32_16x16x32_bf16(paB, vb[fd],           \
                                                        OB_[fd], 0, 0, 0);     \
    }                                                                          \
    __builtin_amdgcn_s_setprio(0);                                             \
  }

#define FA_PHASE(T_, OA_, OB_, MA_, MB_, LA_, LB_)                             \
  {                                                                            \
    const int q0p = (T_) * 32;                                                 \
    const int qrA = q0p + lo, qrB = q0p + 16 + lo;                             \
    const int nkt = (T_) + 1;                                                  \
    const int ch = (nkt + 1) >> 1;                                             \
    const int k0 = w ? ch : 0;                                                 \
    const int k1 = w ? nkt : ch;                                               \
    bf16x8 qfA0, qfA1, qfB0, qfB1;                                             \
    {                                                                          \
      bf16x8 va0 = *(const bf16x8*)(Qp + (size_t)qrA * LD + hi * 8);           \
      bf16x8 va1 = *(const bf16x8*)(Qp + (size_t)qrA * LD + 32 + hi * 8);      \
      bf16x8 vb0 = *(const bf16x8*)(Qp + (size_t)qrB * LD + hi * 8);           \
      bf16x8 vb1 = *(const bf16x8*)(Qp + (size_t)qrB * LD + 32 + hi * 8);      \
      _Pragma("unroll")                                                        \
      for (int j = 0; j < 8; j++){                                             \
        qfA0[j] = (__bf16)((float)va0[j] * QSC);                               \
        qfA1[j] = (__bf16)((float)va1[j] * QSC);                               \
        qfB0[j] = (__bf16)((float)vb0[j] * QSC);                               \
        qfB1[j] = (__bf16)((float)vb1[j] * QSC);                               \
      }                                                                        \
    }                                                                          \
    float lparA = 0.f, lparB = 0.f;                                            \
    MA_ = -1e30f; MB_ = -1e30f;                                                \
    bf16x8 kbA[4], kbB[4];                                                     \
    int kt = k0;                                                               \
    if (kt < k1){                                                              \
      FA_STAGE(kt);                                                            \
      if (kt + 1 < k1) FA_STAGE(kt + 1);                                       \
      FA_DSREAD(kbA, kt);                                                      \
      while (true){                                                            \
        FA_BODY(kbA, kbB, kt, OA_, OB_, MA_, MB_);                             \
        kt++;                                                                  \
        if (kt >= k1) break;                                                   \
        FA_BODY(kbB, kbA, kt, OA_, OB_, MA_, MB_);                             \
        kt++;                                                                  \
        if (kt >= k1) break;                                                   \
      }                                                                        \
    }                                                                          \
    lparA += __shfl_xor(lparA, 16, 64); lparA += __shfl_xor(lparA, 32, 64);    \
    lparB += __shfl_xor(lparB, 16, 64); lparB += __shfl_xor(lparB, 32, 64);    \
    LA_ = lparA; LB_ = lparB;                                                  \
  }

#define FA_WRITEPART(slot_, OA_, OB_, MA_, MB_, LA_, LB_)                      \
  {                                                                            \
    _Pragma("unroll")                                                          \
    for (int fd = 0; fd < 4; fd++){                                            \
      u16x4 pkA, pkB;                                                          \
      _Pragma("unroll")                                                        \
      for (int r = 0; r < 4; r++){                                             \
        pkA[r] = f2bf(OA_[fd][r]); pkB[r] = f2bf(OB_[fd][r]);                  \
      }                                                                        \
      *(u16x4*)((char*)&Xo[slot_][0] + (fd * 16 + lo) * 72 + hi * 8) = pkA;    \
      *(u16x4*)((char*)&Xo[slot_][0] + (fd * 16 + lo) * 72 + 32 + hi * 8) = pkB;\
    }                                                                          \
    if (hi == 0){                                                              \
      Xm[slot_][lo] = MA_;      Xl[slot_][lo] = LA_;                           \
      Xm[slot_][16 + lo] = MB_; Xl[slot_][16 + lo] = LB_;                      \
    }                                                                          \
  }

#define FA_COMBINE(slot_, T_, OA_, OB_, MA_, MB_, LA_, LB_)                    \
  {                                                                            \
    const int q0p = (T_) * 32;                                                 \
    u16x4 pA[4], pB[4];                                                        \
    _Pragma("unroll")                                                          \
    for (int fd = 0; fd < 4; fd++){                                            \
      pA[fd] = *(const u16x4*)((const char*)&Xo[slot_][0] +                    \
                               (fd * 16 + lo) * 72 + hi * 8);                  \
      pB[fd] = *(const u16x4*)((const char*)&Xo[slot_][0] +                    \
                               (fd * 16 + lo) * 72 + 32 + hi * 8);             \
    }                                                                          \
    _Pragma("unroll")                                                          \
    for (int r = 0; r < 4; r++){                                               \
      float mOA = __shfl(MA_, hi * 4 + r, 64);                                 \
      float lOA = __shfl(LA_, hi * 4 + r, 64);                                 \
      float mOB = __shfl(MB_, hi * 4 + r, 64);                                 \
      float lOB = __shfl(LB_, hi * 4 + r, 64);                                 \
      float mPA = Xm[slot_][hi * 4 + r], lPA = Xl[slot_][hi * 4 + r];          \
      float mPB = Xm[slot_][16 + hi * 4 + r], lPB = Xl[slot_][16 + hi * 4 + r];\
      float MfA = fmaxf(mOA, mPA), MfB = fmaxf(mOB, mPB);                      \
      float c0A = fexp2(mOA - MfA), c1A = fexp2(mPA - MfA);                    \
      float c0B = fexp2(mOB - MfB), c1B = fexp2(mPB - MfB);                    \
      float invA = 1.0f / (lOA * c0A + lPA * c1A);                             \
      float invB = 1.0f / (lOB * c0B + lPB * c1B);                             \
      int srA = q0p + hi * 4 + r;                                              \
      int srB = q0p + 16 + hi * 4 + r;                                         \
      u16* orA = Oout + (size_t)(b * S + srA) * 1024 + h * 64;                 \
      u16* orB = Oout + (size_t)(b * S + srB) * 1024 + h * 64;                 \
      _Pragma("unroll")                                                        \
      for (int fd = 0; fd < 4; fd++){                                          \
        float vA = (OA_[fd][r] * c0A + bf2f(pA[fd][r]) * c1A) * invA;          \
        float vB = (OB_[fd][r] * c0B + bf2f(pB[fd][r]) * c1B) * invB;          \
        orA[fd * 16 + lo] = f2bf(vA);                                          \
        orB[fd * 16 + lo] = f2bf(vB);                                          \
      }                                                                        \
    }                                                                          \
  }

__global__ __launch_bounds__(128, 2) void flash_attn(const u16* __restrict__ qkv,
                                                     const u16* __restrict__ vT,
                                                     u16* __restrict__ Oout){
  const int S = 2048, LD = 3072;
  const int L = blockIdx.x;
  const int bh = L & 31;
  const int bx = L >> 5;                    // 0..31
  const int b = bh >> 4, h = bh & 15;
  const u16* base = qkv + (size_t)b * S * LD;
  const u16* Qp = base + h * 64;
  const u16* Kp = base + 1024 + h * 64;
  const u16* Vb = vT + (size_t)bh * 64 * S;
  const int tid = threadIdx.x, w = tid >> 6, l = tid & 63;
  const int lo = l & 15, hi = l >> 4;
  __shared__ u16 Ks[2][2][32 * 64];         // [wave][buf]
  __shared__ u16 Ps[2][2][16 * 36];         // [wave][subtile]
  __shared__ u16 Xo[2][64 * 36];            // [slot] partial O, 72B rows
  __shared__ float Xm[2][32], Xl[2][32];

  const float QSC = 0.125f * 1.44269504089f;
  const int srow8 = l >> 3;
  const int scs = (l & 7) ^ srow8;

  f32x4 o1A[4] = {}, o1B[4] = {};           // phase1 (T0) partial
  f32x4 o2A[4] = {}, o2B[4] = {};           // phase2 (T1) partial
  float m1A, m1B, l1A, l1B, m2A, m2B, l2A, l2B;

  FA_PHASE(63 - bx, o1A, o1B, m1A, m1B, l1A, l1B);
  if (w == 1) FA_WRITEPART(0, o1A, o1B, m1A, m1B, l1A, l1B);
  FA_PHASE(bx,      o2A, o2B, m2A, m2B, l2A, l2B);
  if (w == 0) FA_WRITEPART(1, o2A, o2B, m2A, m2B, l2A, l2B);
  __syncthreads();
  if (w == 0){
    FA_COMBINE(0, 63 - bx, o1A, o1B, m1A, m1B, l1A, l1B);
  } else {
    FA_COMBINE(1, bx,      o2A, o2B, m2A, m2B, l2A, l2B);
  }
}

extern "C" void kernel_launch(void* const* d_in, const int* in_sizes, int n_in,
                              void* d_out, int out_size, void* d_ws, size_t ws_size,
                              hipStream_t stream){
  const float* x     = (const float*)d_in[0];
  const float* w_qkv = (const float*)d_in[1];
  const float* b_qkv = (const float*)d_in[2];
  const float* w_out = (const float*)d_in[3];
  const float* b_out = (const float*)d_in[4];
  const float* cosb  = (const float*)d_in[5];
  const float* sinb  = (const float*)d_in[6];
  // d_in[7] = mask: causal, implemented analytically.
  float* out = (float*)d_out;
  char* ws = (char*)d_ws;
  u16* qkv  = (u16*)(ws);               // bf16 [4096][3072]   25.2 MB
  u16* attn = (u16*)(ws + 25165824);    // bf16 [4096][1024]    8.4 MB
  u16* xbf  = attn;                     // x bf16 — dead before flash writes attn
  u16* wT2  = (u16*)(ws + 33554432);    // w_out^T bf16 [1024][1024]  2.1 MB
  u16* wT1  = (u16*)(ws + 35651584);    // w_qkv^T bf16 [3072][1024]  6.3 MB

  const bool fuse = ws_size >= (size_t)50331648;   // 48 MB
  u16* vT = fuse ? (u16*)(ws + 41943040)           // after wT1
                 : (u16*)(ws + 35651584);          // alias wT1 (dead post-GEMM1)

  prep<<<3072, 256, 0, stream>>>(w_qkv, w_out, x, wT1, wT2, xbf);
  gemm_bt<false, true ><<<dim3(24, 32), 256, 0, stream>>>(
      xbf, wT1, b_qkv, qkv, 4096, 3072, 1024, cosb, sinb, fuse ? vT : nullptr);
  if (!fuse)
    v_transpose<<<dim3(32, 32), 256, 0, stream>>>(qkv, vT);
  flash_attn<<<1024, 128, 0, stream>>>(qkv, vT, attn);
  gemm_bt<true , false><<<dim3(8, 32), 256, 0, stream>>>(
      attn, wT2, b_out, out, 4096, 1024, 1024, cosb, sinb, nullptr);
}